// Round 1
// baseline (263.776 us; speedup 1.0000x reference)
//
#include <hip/hip_runtime.h>
#include <math.h>

#define IMSIZE 64
#define S_SIZE 4096
#define A_SZ 8
#define C_SZ 10
#define B_SIZE 32
#define SB 128
#define VI_K 30
#define GAMMA 0.99f

// ---------------------------------------------------------------------------
// Layout: v / sar / coef stored as [g][s][b8] with g = b/8, b8 = b%8.
// So 8 batches of one state are 8 consecutive floats (8 distinct LDS banks).
// ---------------------------------------------------------------------------

__global__ void init_kernel(const float* __restrict__ x,
                            const float* __restrict__ conv_w,
                            const float* __restrict__ conv_b,
                            float* __restrict__ sar_ws,
                            float* __restrict__ coef_ws,
                            float* __restrict__ v0) {
    int t = blockIdx.x * blockDim.x + threadIdx.x;   // 0 .. B*S-1
    int b = t >> 12;
    int s = t & (S_SIZE - 1);
    int y = s >> 6, xx = s & 63;

    // 3x3 SAME conv over 2 input channels
    float acc = conv_b[0];
#pragma unroll
    for (int ic = 0; ic < 2; ++ic) {
        const float* xp = x + ((b * 2 + ic) << 12);
#pragma unroll
        for (int ky = 0; ky < 3; ++ky) {
            int yy = y + ky - 1;
            if (yy < 0 || yy >= IMSIZE) continue;
#pragma unroll
            for (int kx = 0; kx < 3; ++kx) {
                int xc = xx + kx - 1;
                if (xc < 0 || xc >= IMSIZE) continue;
                acc += xp[(yy << 6) + xc] * conv_w[(ic * 3 + ky) * 3 + kx];
            }
        }
    }
    float x1 = x[((b * 2 + 1) << 12) + s];
    float coef = GAMMA * (1.0f - x1 * 0.1f);   // GAMMA folded here

    int g = b >> 3, b8 = b & 7;
    int o = (((g << 12) + s) << 3) + b8;
    sar_ws[o]  = acc;
    coef_ws[o] = coef;
    v0[o]      = acc;   // v0 = sar
}

// Packed transition table: (idx*8, prob) per (s,a,c)
__global__ void pack_kernel(const int* __restrict__ ds_state,
                            const int* __restrict__ ds_prob,
                            const float* __restrict__ pv,
                            int2* __restrict__ pk) {
    int i = blockIdx.x * blockDim.x + threadIdx.x;
    if (i >= S_SIZE * A_SZ * C_SZ) return;
    int idx = ds_state[i];
    float p = pv[ds_prob[i]];
    p = fminf(fmaxf(p, 0.0f), 1.0f);
    int2 e;
    e.x = idx << 3;                // pre-multiplied by 8 (batch stride in LDS)
    e.y = __float_as_int(p);
    pk[i] = e;
}

// One VI step: v_out = max_a ( sar + coef * sum_c p * v_in[cf] )
// grid = 256 blocks: blockIdx = slice*4 + g  (4 batch groups x 64 s-slices)
// block = 512 threads: tid%8 = batch lane, tid/8 = local state (64 states)
__global__ __launch_bounds__(512) void vi_kernel(const float* __restrict__ vin,
                                                 float* __restrict__ vout,
                                                 const float* __restrict__ sar_ws,
                                                 const float* __restrict__ coef_ws,
                                                 const int2* __restrict__ pk) {
    __shared__ float vld[S_SIZE * 8];   // 128 KiB: full v for this batch group
    int g = blockIdx.x & 3;
    int slice = blockIdx.x >> 2;        // 0..63
    int tid = threadIdx.x;

    // stage v (32768 floats) coalesced via float4
    const float4* src = (const float4*)(vin + (g << 15));
    float4* dst = (float4*)vld;
#pragma unroll
    for (int k = 0; k < 16; ++k)
        dst[tid + (k << 9)] = src[tid + (k << 9)];
    __syncthreads();

    int b8 = tid & 7;
    int w = tid >> 3;                   // 0..63
    int s = (slice << 6) + w;
    int o = (((g << 12) + s) << 3) + b8;
    float sar = sar_ws[o];
    float coef = coef_ws[o];
    const int2* __restrict__ row = pk + s * (A_SZ * C_SZ);

    float vmax = -INFINITY;
#pragma unroll
    for (int a = 0; a < A_SZ; ++a) {
        float acc = 0.0f;
#pragma unroll
        for (int c = 0; c < C_SZ; ++c) {
            int2 e = row[a * C_SZ + c];
            acc += __int_as_float(e.y) * vld[e.x + b8];
        }
        vmax = fmaxf(vmax, fmaf(coef, acc, sar));
    }
    vout[o] = vmax;
}

// Final: q30 = f(v29) at the 128 gathered states per batch, fused linear+res.
__global__ void out_kernel(const float* __restrict__ v29,
                           const float* __restrict__ sar_ws,
                           const float* __restrict__ coef_ws,
                           const int2* __restrict__ pk,
                           const int* __restrict__ s1,
                           const int* __restrict__ s2,
                           const float* __restrict__ lin_w,
                           const float* __restrict__ lin_b,
                           float* __restrict__ out) {
    int t = blockIdx.x * blockDim.x + threadIdx.x;   // 0..4095
    if (t >= B_SIZE * SB) return;
    int b = t >> 7;
    int s = s1[t] * IMSIZE + s2[t];
    int g = b >> 3, b8 = b & 7;
    int o = (((g << 12) + s) << 3) + b8;
    float sar = sar_ws[o];
    float coef = coef_ws[o];
    const float* vbase = v29 + (g << 15) + b8;
    const int2* __restrict__ row = pk + s * (A_SZ * C_SZ);

    float q[A_SZ];
#pragma unroll
    for (int a = 0; a < A_SZ; ++a) {
        float acc = 0.0f;
#pragma unroll
        for (int c = 0; c < C_SZ; ++c) {
            int2 e = row[a * C_SZ + c];
            acc += __int_as_float(e.y) * vbase[e.x];
        }
        q[a] = fmaf(coef, acc, sar);
    }
#pragma unroll
    for (int i = 0; i < A_SZ; ++i) {
        float accl = lin_b[i] + q[i];
#pragma unroll
        for (int a = 0; a < A_SZ; ++a)
            accl += q[a] * lin_w[i * 8 + a];
        out[t * 8 + i] = accl;
    }
}

extern "C" void kernel_launch(void* const* d_in, const int* in_sizes, int n_in,
                              void* d_out, int out_size, void* d_ws, size_t ws_size,
                              hipStream_t stream) {
    const float* x       = (const float*)d_in[0];
    const int*   s1      = (const int*)d_in[1];
    const int*   s2      = (const int*)d_in[2];
    const int*   ds_state= (const int*)d_in[3];
    const int*   ds_prob = (const int*)d_in[4];
    const float* conv_w  = (const float*)d_in[5];
    const float* conv_b  = (const float*)d_in[6];
    const float* pv      = (const float*)d_in[7];
    const float* lin_w   = (const float*)d_in[8];
    const float* lin_b   = (const float*)d_in[9];
    float* out = (float*)d_out;

    // workspace carve-up (bytes)
    const size_t VSZ = (size_t)B_SIZE * S_SIZE * 4;      // 512 KiB
    char* ws = (char*)d_ws;
    float* vA      = (float*)(ws);
    float* vB      = (float*)(ws + VSZ);
    float* sar_ws  = (float*)(ws + 2 * VSZ);
    float* coef_ws = (float*)(ws + 3 * VSZ);
    int2*  pk      = (int2*) (ws + 4 * VSZ);             // 2.62 MiB

    // init: sar/coef/v0
    init_kernel<<<(B_SIZE * S_SIZE) / 256, 256, 0, stream>>>(
        x, conv_w, conv_b, sar_ws, coef_ws, vA);
    // pack transition table
    pack_kernel<<<(S_SIZE * A_SZ * C_SZ + 255) / 256, 256, 0, stream>>>(
        ds_state, ds_prob, pv, pk);

    // 29 value-iteration steps (v0 -> v29), ping-pong
    float* vin = vA;
    float* vout = vB;
    for (int i = 0; i < VI_K - 1; ++i) {
        vi_kernel<<<256, 512, 0, stream>>>(vin, vout, sar_ws, coef_ws, pk);
        float* tmp = vin; vin = vout; vout = tmp;
    }
    // after loop, vin holds v29

    // final q30 at gathered states + linear + residual
    out_kernel<<<(B_SIZE * SB + 255) / 256, 256, 0, stream>>>(
        vin, sar_ws, coef_ws, pk, s1, s2, lin_w, lin_b, out);
}